// Round 5
// baseline (957.332 us; speedup 1.0000x reference)
//
#include <hip/hip_runtime.h>
#include <hip/hip_bf16.h>
#include <math.h>

#define NEG_SLOPE 0.2f
#define NPB_SHIFT 7
#define NPB 128          // nodes per bucket
#define SC_EDGES 16384   // edges per bscatter block

template <typename T>
__device__ __forceinline__ T ntload(const T* p) { return __builtin_nontemporal_load(p); }
template <typename T>
__device__ __forceinline__ void ntstore(T* p, T v) { __builtin_nontemporal_store(v, p); }

// ---------------------------------------------------------------------------
// filt[l][c][r] = softmax_r(gt_w[l][c][:])
// ---------------------------------------------------------------------------
__global__ void mkfilt(const float* __restrict__ gt_w, float* __restrict__ filt,
                       int rows) {
    int i = threadIdx.x;
    if (i < rows) {
        const float* g = gt_w + i * 3;
        float m = fmaxf(g[0], fmaxf(g[1], g[2]));
        float e0 = __expf(g[0] - m), e1 = __expf(g[1] - m), e2 = __expf(g[2] - m);
        float s = e0 + e1 + e2;
        filt[i * 3 + 0] = e0 / s;
        filt[i * 3 + 1] = e1 / s;
        filt[i * 3 + 2] = e2 / s;
    }
}

// ---------------------------------------------------------------------------
// Wc[c] = params[c] @ fc_w
// ---------------------------------------------------------------------------
__global__ __launch_bounds__(256) void combw_kernel(const float* __restrict__ params,
                                                    const float* __restrict__ fc_w,
                                                    float* __restrict__ Wc) {
    __shared__ __align__(16) float sP[64 * 64], sF[64 * 64];
    const float* P = params + (size_t)blockIdx.x * 64 * 64;
    int t = threadIdx.x;
    for (int i = t * 4; i < 4096; i += 1024) {
        *(float4*)&sP[i] = *(const float4*)&P[i];
        *(float4*)&sF[i] = *(const float4*)&fc_w[i];
    }
    __syncthreads();
    float* O = Wc + (size_t)blockIdx.x * 64 * 64;
    for (int i = t; i < 4096; i += 256) {
        int r = i >> 6, c = i & 63;
        float acc = 0.f;
#pragma unroll
        for (int k = 0; k < 64; ++k) acc += sP[r * 64 + k] * sF[k * 64 + c];
        O[i] = acc;
    }
}

// ---------------------------------------------------------------------------
// Bucketed CSR build
// ---------------------------------------------------------------------------
__global__ __launch_bounds__(256) void bcount_kernel(const int* __restrict__ dst,
                                                     int* __restrict__ bcnt, int m, int NB) {
    __shared__ int h[1024];
    for (int i = threadIdx.x; i < NB; i += 256) h[i] = 0;
    __syncthreads();
    int base = blockIdx.x * SC_EDGES;
    int endi = base + SC_EDGES; if (endi > m) endi = m;
    for (int i = base + threadIdx.x; i < endi; i += 256)
        atomicAdd(&h[ntload(&dst[i]) >> NPB_SHIFT], 1);
    __syncthreads();
    for (int i = threadIdx.x; i < NB; i += 256)
        if (h[i]) atomicAdd(&bcnt[i], h[i]);
}

__global__ __launch_bounds__(1024) void bscan_kernel(const int* __restrict__ bcnt,
                                                     int* __restrict__ bbase,
                                                     int* __restrict__ bcur, int NB) {
    __shared__ int s[1024];
    int t = threadIdx.x;
    int v = (t < NB) ? bcnt[t] : 0;
    s[t] = v;
    __syncthreads();
    for (int off = 1; off < 1024; off <<= 1) {
        int u = (t >= off) ? s[t - off] : 0;
        __syncthreads();
        s[t] += u;
        __syncthreads();
    }
    if (t < NB) { bbase[t] = s[t] - v; bcur[t] = s[t] - v; }
    if (t == 1023) bbase[NB] = s[1023];
}

// two-pass: LDS histogram over 16K edges -> reserve -> scatter (contiguous per bucket)
__global__ __launch_bounds__(256) void bscatter_kernel(const int* __restrict__ src,
                                                       const int* __restrict__ dst,
                                                       const int* __restrict__ rel,
                                                       int* __restrict__ bcur,
                                                       unsigned* __restrict__ ebuf,
                                                       int m, int NB) {
    __shared__ int cnt[1024];
    for (int i = threadIdx.x; i < NB; i += 256) cnt[i] = 0;
    __syncthreads();
    int base = blockIdx.x * SC_EDGES;
    int endi = base + SC_EDGES; if (endi > m) endi = m;
    for (int i = base + threadIdx.x; i < endi; i += 256)
        atomicAdd(&cnt[dst[i] >> NPB_SHIFT], 1);
    __syncthreads();
    for (int b = threadIdx.x; b < NB; b += 256) {
        int c = cnt[b];
        if (c) cnt[b] = atomicAdd(&bcur[b], c);
    }
    __syncthreads();
    for (int i = base + threadIdx.x; i < endi; i += 256) {
        int d = dst[i];
        int bk = d >> NPB_SHIFT;
        unsigned pk = (unsigned)src[i] | ((unsigned)rel[i] << 17) |
                      ((unsigned)(d & (NPB - 1)) << 19);
        int pos = atomicAdd(&cnt[bk], 1);
        ebuf[pos] = pk;
    }
}

__global__ __launch_bounds__(256) void bfinal_kernel(const unsigned* __restrict__ ebuf,
                                                     const int* __restrict__ bbase,
                                                     int* __restrict__ rowp,
                                                     unsigned* __restrict__ csr,
                                                     int n, int m, int NB) {
    __shared__ int cnt[NPB], cur[NPB], sc[NPB];
    int b = blockIdx.x;
    int t = threadIdx.x;
    int e0 = bbase[b], e1 = bbase[b + 1];
    if (t < NPB) cnt[t] = 0;
    __syncthreads();
    for (int j = e0 + t; j < e1; j += 256)
        atomicAdd(&cnt[(ebuf[j] >> 19) & (NPB - 1)], 1);
    __syncthreads();
    int v0 = (t < NPB) ? cnt[t] : 0;
    if (t < NPB) sc[t] = v0;
    __syncthreads();
    for (int off = 1; off < NPB; off <<= 1) {
        int u = (t >= off && t < NPB) ? sc[t - off] : 0;
        __syncthreads();
        if (t < NPB) sc[t] += u;
        __syncthreads();
    }
    if (t < NPB) {
        int ex = e0 + sc[t] - v0;
        cur[t] = ex;
        int v = b * NPB + t;
        if (v < n) rowp[v] = ex;
    }
    if (b == 0 && t == 0) rowp[n] = m;
    __syncthreads();
    for (int j = e0 + t; j < e1; j += 256) {
        unsigned pk = ebuf[j];
        int dl = (pk >> 19) & (NPB - 1);
        int pos = atomicAdd(&cur[dl], 1);
        csr[pos] = (pk & 0x1FFFF) | (((pk >> 17) & 3) << 20);
    }
}

// ---------------------------------------------------------------------------
// GEMM: C[n,64] = A[n,64] @ W[64,64], 128-row tiles, 8x4 acc per thread.
// Optional fused el/er epilogue into packed el2/er2 ([node][2], slot ch).
// ---------------------------------------------------------------------------
__global__ __launch_bounds__(256) void gemm128(const float* __restrict__ A,
                                               const float* __restrict__ W,
                                               float* __restrict__ C, int n,
                                               const float* __restrict__ attn_l,
                                               const float* __restrict__ attn_r,
                                               float* __restrict__ el2,
                                               float* __restrict__ er2, int ch) {
    __shared__ __align__(16) float sW[64 * 64];
    __shared__ __align__(16) float sA[128 * 68];
    __shared__ float sAl[64], sAr[64];
    int t = threadIdx.x;
    int row0 = blockIdx.x * 128;
    for (int i = t * 4; i < 4096; i += 1024)
        *(float4*)&sW[i] = *(const float4*)&W[i];
    if (el2 && t < 64) { sAl[t] = attn_l[t]; sAr[t] = attn_r[t]; }
    int rows = n - row0; if (rows > 128) rows = 128;
    for (int i = t * 4; i < 8192; i += 1024) {
        int r = i >> 6, cc = i & 63;
        float4 v = {0.f, 0.f, 0.f, 0.f};
        if (r < rows) v = *(const float4*)&A[(size_t)(row0 + r) * 64 + cc];
        *(float4*)&sA[r * 68 + cc] = v;
    }
    __syncthreads();
    int tr = (t >> 4) * 8;    // 16 row-groups x 8 rows = 128
    int tc = (t & 15) * 4;    // 16 col-groups x 4 cols = 64
    float acc[8][4] = {};
#pragma unroll 4
    for (int k = 0; k < 64; k += 4) {
        float4 b0 = *(const float4*)&sW[(k + 0) * 64 + tc];
        float4 b1 = *(const float4*)&sW[(k + 1) * 64 + tc];
        float4 b2v = *(const float4*)&sW[(k + 2) * 64 + tc];
        float4 b3 = *(const float4*)&sW[(k + 3) * 64 + tc];
#pragma unroll
        for (int i = 0; i < 8; ++i) {
            float4 a = *(const float4*)&sA[(tr + i) * 68 + k];
            acc[i][0] += a.x * b0.x + a.y * b1.x + a.z * b2v.x + a.w * b3.x;
            acc[i][1] += a.x * b0.y + a.y * b1.y + a.z * b2v.y + a.w * b3.y;
            acc[i][2] += a.x * b0.z + a.y * b1.z + a.z * b2v.z + a.w * b3.z;
            acc[i][3] += a.x * b0.w + a.y * b1.w + a.z * b2v.w + a.w * b3.w;
        }
    }
#pragma unroll
    for (int i = 0; i < 8; ++i) {
        int r = tr + i;
        if (row0 + r < n) {
            float4 v = {acc[i][0], acc[i][1], acc[i][2], acc[i][3]};
            *(float4*)&C[(size_t)(row0 + r) * 64 + tc] = v;
        }
    }
    if (el2) {
        float pl[8], pr[8];
#pragma unroll
        for (int i = 0; i < 8; ++i) {
            float l = 0.f, r = 0.f;
#pragma unroll
            for (int j = 0; j < 4; ++j) {
                l += acc[i][j] * sAl[tc + j];
                r += acc[i][j] * sAr[tc + j];
            }
            pl[i] = l; pr[i] = r;
        }
#pragma unroll
        for (int off = 1; off < 16; off <<= 1) {
#pragma unroll
            for (int i = 0; i < 8; ++i) {
                pl[i] += __shfl_xor(pl[i], off);
                pr[i] += __shfl_xor(pr[i], off);
            }
        }
        if ((t & 15) == 0) {
#pragma unroll
            for (int i = 0; i < 8; ++i) {
                int r = row0 + tr + i;
                if (r < n) {
                    el2[(size_t)r * 2 + ch] = pl[i];
                    er2[(size_t)r * 2 + ch] = pr[i];
                }
            }
        }
    }
}

// ---------------------------------------------------------------------------
// GAT pass 1 (NCH channels), one wave per dst node.
// ---------------------------------------------------------------------------
template <int NCH>
__global__ __launch_bounds__(256) void agg1_k(
        const int* __restrict__ rowp, const unsigned* __restrict__ csr,
        const float* __restrict__ filt, int fo0, int fo1,
        const float* __restrict__ el2, const float* __restrict__ er2,
        const float* __restrict__ ftA, float* __restrict__ oA,
        float* __restrict__ abA, float* __restrict__ sbA,
        const float* __restrict__ ftB, float* __restrict__ oB,
        float* __restrict__ abB, float* __restrict__ sbB, int n) {
    int w = (blockIdx.x * blockDim.x + threadIdx.x) >> 6;
    int lane = threadIdx.x & 63;
    if (w >= n) return;
    int base = rowp[w], end = rowp[w + 1];
    float fA0 = filt[fo0], fA1 = filt[fo0 + 1], fA2 = filt[fo0 + 2];
    float fB0 = 0.f, fB1 = 0.f, fB2 = 0.f;
    if (NCH == 2) { fB0 = filt[fo1]; fB1 = filt[fo1 + 1]; fB2 = filt[fo1 + 2]; }
    float2 erv = *(const float2*)&er2[(size_t)w * 2];

    // lane-parallel: degw, unnormalized attention e -> abuf, softmax denom
    float degA = 0.f, ssA = 0.f, degB = 0.f, ssB = 0.f;
    for (int j = base + lane; j < end; j += 64) {
        unsigned pk = ntload(&csr[j]);
        int s = pk & 0xFFFFF;
        int r = pk >> 20;
        float2 e2 = *(const float2*)&el2[(size_t)s * 2];
        degA += (r == 0) ? fA0 : ((r == 1) ? fA1 : fA2);
        float x = e2.x + erv.x;
        float e = __expf(x > 0.f ? x : NEG_SLOPE * x);
        ntstore(&abA[j], e); ssA += e;
        if (NCH == 2) {
            degB += (r == 0) ? fB0 : ((r == 1) ? fB1 : fB2);
            float xb = e2.y + erv.y;
            float eb = __expf(xb > 0.f ? xb : NEG_SLOPE * xb);
            ntstore(&abB[j], eb); ssB += eb;
        }
    }
    for (int off = 32; off; off >>= 1) {
        degA += __shfl_xor(degA, off); ssA += __shfl_xor(ssA, off);
        if (NCH == 2) { degB += __shfl_xor(degB, off); ssB += __shfl_xor(ssB, off); }
    }

    // serial gather, feature-parallel, unroll 8
    float accA = 0.f, accB = 0.f;
    int j = base;
    for (; j + 8 <= end; j += 8) {
        int s[8]; float wA[8], wB[8];
#pragma unroll
        for (int q = 0; q < 8; ++q) {
            unsigned pk = ntload(&csr[j + q]);
            s[q] = pk & 0xFFFFF;
            int r = pk >> 20;
            wA[q] = (r == 0) ? fA0 : ((r == 1) ? fA1 : fA2);
            if (NCH == 2) wB[q] = (r == 0) ? fB0 : ((r == 1) ? fB1 : fB2);
        }
#pragma unroll
        for (int q = 0; q < 8; ++q) accA += wA[q] * ftA[(size_t)s[q] * 64 + lane];
        if (NCH == 2) {
#pragma unroll
            for (int q = 0; q < 8; ++q) accB += wB[q] * ftB[(size_t)s[q] * 64 + lane];
        }
    }
    for (; j < end; ++j) {
        unsigned pk = ntload(&csr[j]);
        int s = pk & 0xFFFFF;
        int r = pk >> 20;
        float wA = (r == 0) ? fA0 : ((r == 1) ? fA1 : fA2);
        accA += wA * ftA[(size_t)s * 64 + lane];
        if (NCH == 2) {
            float wB = (r == 0) ? fB0 : ((r == 1) ? fB1 : fB2);
            accB += wB * ftB[(size_t)s * 64 + lane];
        }
    }
    float dA = degA > 0.f ? degA : 1.f;
    ntstore(&oA[(size_t)w * 64 + lane], accA / dA);
    if (lane == 0) sbA[w] = (ssA > 0.f) ? 1.f / ssA : 0.f;
    if (NCH == 2) {
        float dB = degB > 0.f ? degB : 1.f;
        ntstore(&oB[(size_t)w * 64 + lane], accB / dB);
        if (lane == 0) sbB[w] = (ssB > 0.f) ? 1.f / ssB : 0.f;
    }
}

// ---------------------------------------------------------------------------
// GAT pass 2 (NCH channels)
// ---------------------------------------------------------------------------
template <int NCH>
__global__ __launch_bounds__(256) void agg2_k(
        const int* __restrict__ rowp, const unsigned* __restrict__ csr,
        const float* __restrict__ ftA, const float* __restrict__ abA,
        const float* __restrict__ sbA, float* __restrict__ oA,
        const float* __restrict__ ftB, const float* __restrict__ abB,
        const float* __restrict__ sbB, float* __restrict__ oB, int n) {
    int w = (blockIdx.x * blockDim.x + threadIdx.x) >> 6;
    int lane = threadIdx.x & 63;
    if (w >= n) return;
    int base = rowp[w], end = rowp[w + 1];
    float invA = sbA[w];
    float invB = (NCH == 2) ? sbB[w] : 0.f;
    float accA = 0.f, accB = 0.f;
    int j = base;
    for (; j + 8 <= end; j += 8) {
        int s[8]; float aA[8], aB[8];
#pragma unroll
        for (int q = 0; q < 8; ++q) {
            unsigned pk = ntload(&csr[j + q]);
            s[q] = pk & 0xFFFFF;
            aA[q] = ntload(&abA[j + q]);
            if (NCH == 2) aB[q] = ntload(&abB[j + q]);
        }
#pragma unroll
        for (int q = 0; q < 8; ++q) accA += aA[q] * ftA[(size_t)s[q] * 64 + lane];
        if (NCH == 2) {
#pragma unroll
            for (int q = 0; q < 8; ++q) accB += aB[q] * ftB[(size_t)s[q] * 64 + lane];
        }
    }
    for (; j < end; ++j) {
        unsigned pk = ntload(&csr[j]);
        int s = pk & 0xFFFFF;
        accA += ntload(&abA[j]) * ftA[(size_t)s * 64 + lane];
        if (NCH == 2) accB += ntload(&abB[j]) * ftB[(size_t)s * 64 + lane];
    }
    ntstore(&oA[(size_t)w * 64 + lane], accA * invA);
    if (NCH == 2) ntstore(&oB[(size_t)w * 64 + lane], accB * invB);
}

// ---------------------------------------------------------------------------
// Fused final: out = b2 + (lw0*A0 + lw1*A1) @ W2
// ---------------------------------------------------------------------------
__global__ __launch_bounds__(256) void gemm_out2(const float* __restrict__ A0,
                                                 const float* __restrict__ A1,
                                                 const float* __restrict__ W2,
                                                 const float* __restrict__ b2,
                                                 const float* __restrict__ lin_w,
                                                 float* __restrict__ out, int n) {
    __shared__ __align__(16) float sW[64 * 50];
    __shared__ __align__(16) float sA[64 * 68];
    int t = threadIdx.x;
    int row0 = blockIdx.x * 64;
    float lw0 = lin_w[0], lw1 = lin_w[1];
    for (int i = t; i < 64 * 50; i += 256) sW[i] = W2[i];
    int rows = n - row0; if (rows > 64) rows = 64;
    for (int i = t * 4; i < 4096; i += 1024) {
        int r = i >> 6, cc = i & 63;
        float4 v = {0.f, 0.f, 0.f, 0.f};
        if (r < rows) {
            float4 a = *(const float4*)&A0[(size_t)(row0 + r) * 64 + cc];
            float4 b = *(const float4*)&A1[(size_t)(row0 + r) * 64 + cc];
            v.x = lw0 * a.x + lw1 * b.x; v.y = lw0 * a.y + lw1 * b.y;
            v.z = lw0 * a.z + lw1 * b.z; v.w = lw0 * a.w + lw1 * b.w;
        }
        *(float4*)&sA[r * 68 + cc] = v;
    }
    __syncthreads();
    for (int i = t; i < 64 * 50; i += 256) {
        int r = i / 50, col = i - r * 50;
        if (row0 + r >= n) continue;
        float acc = 0.f;
#pragma unroll
        for (int k = 0; k < 64; ++k) acc += sA[r * 68 + k] * sW[k * 50 + col];
        out[(size_t)(row0 + r) * 50 + col] = b2[col] + acc;
    }
}

// per-channel fallback
__global__ __launch_bounds__(256) void gemm_out(const float* __restrict__ A,
                                                const float* __restrict__ W2,
                                                const float* __restrict__ b2,
                                                const float* __restrict__ lin_w,
                                                float* __restrict__ out, int n, int c) {
    __shared__ __align__(16) float sW[64 * 50];
    __shared__ __align__(16) float sA[64 * 68];
    int t = threadIdx.x;
    int row0 = blockIdx.x * 64;
    for (int i = t; i < 64 * 50; i += 256) sW[i] = W2[i];
    int rows = n - row0; if (rows > 64) rows = 64;
    for (int i = t * 4; i < 4096; i += 1024) {
        int r = i >> 6, cc = i & 63;
        float4 v = {0.f, 0.f, 0.f, 0.f};
        if (r < rows) v = *(const float4*)&A[(size_t)(row0 + r) * 64 + cc];
        *(float4*)&sA[r * 68 + cc] = v;
    }
    float lw = lin_w[c];
    __syncthreads();
    for (int i = t; i < 64 * 50; i += 256) {
        int r = i / 50, col = i - r * 50;
        if (row0 + r >= n) continue;
        float acc = 0.f;
#pragma unroll
        for (int k = 0; k < 64; ++k) acc += sA[r * 68 + k] * sW[k * 50 + col];
        size_t o = (size_t)(row0 + r) * 50 + col;
        float base = (c == 0) ? b2[col] : out[o];
        out[o] = base + lw * acc;
    }
}

// ---------------------------------------------------------------------------
extern "C" void kernel_launch(void* const* d_in, const int* in_sizes, int n_in,
                              void* d_out, int out_size, void* d_ws, size_t ws_size,
                              hipStream_t stream) {
    const float* h      = (const float*)d_in[0];
    const float* params = (const float*)d_in[1];
    const float* gt_w   = (const float*)d_in[2];
    const float* fc_w   = (const float*)d_in[3];
    const float* attn_l = (const float*)d_in[4];
    const float* attn_r = (const float*)d_in[5];
    const float* lin_w  = (const float*)d_in[6];
    const float* W2     = (const float*)d_in[7];
    const float* b2     = (const float*)d_in[8];
    const int*   src    = (const int*)d_in[9];
    const int*   dst    = (const int*)d_in[10];
    const int*   rel    = (const int*)d_in[11];

    const int n = in_sizes[0] / 64;      // 100000 nodes
    const int m = in_sizes[9];           // 1.8M edges
    const int C = 2, L = 2;
    float* out = (float*)d_out;

    char* base = (char*)d_ws;
    size_t off = 0;
    auto alloc = [&](size_t bytes) -> char* {
        char* p = base + off;
        off = (off + bytes + 255) & ~(size_t)255;
        return p;
    };
    const int NB = (n + NPB - 1) >> NPB_SHIFT;       // 782 buckets
    const int nchunks = (m + SC_EDGES - 1) / SC_EDGES;
    // common
    float*    filt  = (float*)alloc(L * C * 3 * sizeof(float));
    float*    Wc    = (float*)alloc((size_t)C * 64 * 64 * 4);
    int*      bcnt  = (int*)alloc((size_t)NB * 4);
    int*      bbase = (int*)alloc((size_t)(NB + 1) * 4);
    int*      bcur  = (int*)alloc((size_t)NB * 4);
    int*      rowp  = (int*)alloc((size_t)(n + 1) * 4);
    unsigned* ebuf  = (unsigned*)alloc((size_t)m * 4);
    unsigned* csr   = (unsigned*)alloc((size_t)m * 4);
    float*    el2   = (float*)alloc((size_t)n * 2 * 4);   // packed [node][2]
    float*    er2   = (float*)alloc((size_t)n * 2 * 4);
    // channel A
    float*    sbA  = (float*)alloc((size_t)n * 4);
    float*    abA  = (float*)alloc((size_t)m * 4);
    float*    A0   = (float*)alloc((size_t)n * 64 * 4);
    float*    B0   = (float*)alloc((size_t)n * 64 * 4);
    float*    C0   = (float*)alloc((size_t)n * 64 * 4);
    // channel B
    float*    sbB  = (float*)alloc((size_t)n * 4);
    float*    abB  = (float*)alloc((size_t)m * 4);
    float*    A1   = (float*)alloc((size_t)n * 64 * 4);
    float*    B1   = (float*)alloc((size_t)n * 64 * 4);
    float*    C1   = (float*)alloc((size_t)n * 64 * 4);
    bool dual = (off <= ws_size);

    // ---- CSR build ----
    hipMemsetAsync(bcnt, 0, (size_t)NB * 4, stream);
    mkfilt<<<1, 64, 0, stream>>>(gt_w, filt, L * C);
    combw_kernel<<<C, 256, 0, stream>>>(params, fc_w, Wc);
    bcount_kernel<<<nchunks, 256, 0, stream>>>(dst, bcnt, m, NB);
    bscan_kernel<<<1, 1024, 0, stream>>>(bcnt, bbase, bcur, NB);
    bscatter_kernel<<<nchunks, 256, 0, stream>>>(src, dst, rel, bcur, ebuf, m, NB);
    bfinal_kernel<<<NB, 256, 0, stream>>>(ebuf, bbase, rowp, csr, n, m, NB);

    const int gB = (n + 127) / 128;
    const int gOut = (n + 63) / 64;
    const int waveBlocks = (n + 3) / 4;

    if (dual) {
        for (int l = 0; l < L; ++l) {
            if (l == 0) {
                gemm128<<<gB, 256, 0, stream>>>(h, Wc, B0, n, attn_l, attn_r, el2, er2, 0);
                gemm128<<<gB, 256, 0, stream>>>(h, Wc + 64 * 64, B1, n,
                                                attn_l, attn_r, el2, er2, 1);
            } else {
                gemm128<<<gB, 256, 0, stream>>>(A0, fc_w, B0, n, attn_l, attn_r, el2, er2, 0);
                gemm128<<<gB, 256, 0, stream>>>(A1, fc_w, B1, n, attn_l, attn_r, el2, er2, 1);
            }
            int fo0 = (l * C + 0) * 3, fo1 = (l * C + 1) * 3;
            agg1_k<2><<<waveBlocks, 256, 0, stream>>>(rowp, csr, filt, fo0, fo1, el2, er2,
                                                      B0, C0, abA, sbA,
                                                      B1, C1, abB, sbB, n);
            agg2_k<2><<<waveBlocks, 256, 0, stream>>>(rowp, csr,
                                                      C0, abA, sbA, A0,
                                                      C1, abB, sbB, A1, n);
        }
        gemm_out2<<<gOut, 256, 0, stream>>>(A0, A1, W2, b2, lin_w, out, n);
    } else {
        for (int c = 0; c < C; ++c) {
            for (int l = 0; l < L; ++l) {
                const float* Ain = (l == 0) ? h : A0;
                const float* Win = (l == 0) ? (Wc + (size_t)c * 64 * 64) : fc_w;
                gemm128<<<gB, 256, 0, stream>>>(Ain, Win, B0, n,
                                                attn_l, attn_r, el2, er2, 0);
                int fo = (l * C + c) * 3;
                agg1_k<1><<<waveBlocks, 256, 0, stream>>>(rowp, csr, filt, fo, fo, el2, er2,
                                                          B0, C0, abA, sbA,
                                                          nullptr, nullptr, nullptr, nullptr, n);
                agg2_k<1><<<waveBlocks, 256, 0, stream>>>(rowp, csr,
                                                          C0, abA, sbA, A0,
                                                          nullptr, nullptr, nullptr, nullptr, n);
            }
            gemm_out<<<gOut, 256, 0, stream>>>(A0, W2, b2, lin_w, out, n, c);
        }
    }
}

// Round 6
// 797.852 us; speedup vs baseline: 1.1999x; 1.1999x over previous
//
#include <hip/hip_runtime.h>
#include <hip/hip_bf16.h>
#include <math.h>

#define NEG_SLOPE 0.2f
#define NPB_SHIFT 7
#define NPB 128          // nodes per bucket
#define SC_EDGES 16384   // edges per bscatter block
#define MAXD 128         // per-node edges staged in LDS (Poisson(18) -> P(>128) ~ 0)

// ---------------------------------------------------------------------------
// filt[l][c][r] = softmax_r(gt_w[l][c][:])
// ---------------------------------------------------------------------------
__global__ void mkfilt(const float* __restrict__ gt_w, float* __restrict__ filt,
                       int rows) {
    int i = threadIdx.x;
    if (i < rows) {
        const float* g = gt_w + i * 3;
        float m = fmaxf(g[0], fmaxf(g[1], g[2]));
        float e0 = __expf(g[0] - m), e1 = __expf(g[1] - m), e2 = __expf(g[2] - m);
        float s = e0 + e1 + e2;
        filt[i * 3 + 0] = e0 / s;
        filt[i * 3 + 1] = e1 / s;
        filt[i * 3 + 2] = e2 / s;
    }
}

// ---------------------------------------------------------------------------
// Wc[c] = params[c] @ fc_w
// ---------------------------------------------------------------------------
__global__ __launch_bounds__(256) void combw_kernel(const float* __restrict__ params,
                                                    const float* __restrict__ fc_w,
                                                    float* __restrict__ Wc) {
    __shared__ __align__(16) float sP[64 * 64], sF[64 * 64];
    const float* P = params + (size_t)blockIdx.x * 64 * 64;
    int t = threadIdx.x;
    for (int i = t * 4; i < 4096; i += 1024) {
        *(float4*)&sP[i] = *(const float4*)&P[i];
        *(float4*)&sF[i] = *(const float4*)&fc_w[i];
    }
    __syncthreads();
    float* O = Wc + (size_t)blockIdx.x * 64 * 64;
    for (int i = t; i < 4096; i += 256) {
        int r = i >> 6, c = i & 63;
        float acc = 0.f;
#pragma unroll
        for (int k = 0; k < 64; ++k) acc += sP[r * 64 + k] * sF[k * 64 + c];
        O[i] = acc;
    }
}

// ---------------------------------------------------------------------------
// Bucketed CSR build
// ---------------------------------------------------------------------------
__global__ __launch_bounds__(256) void bcount_kernel(const int* __restrict__ dst,
                                                     int* __restrict__ bcnt, int m, int NB) {
    __shared__ int h[1024];
    for (int i = threadIdx.x; i < NB; i += 256) h[i] = 0;
    __syncthreads();
    int base = blockIdx.x * SC_EDGES;
    int endi = base + SC_EDGES; if (endi > m) endi = m;
    for (int i = base + threadIdx.x; i < endi; i += 256)
        atomicAdd(&h[dst[i] >> NPB_SHIFT], 1);
    __syncthreads();
    for (int i = threadIdx.x; i < NB; i += 256)
        if (h[i]) atomicAdd(&bcnt[i], h[i]);
}

__global__ __launch_bounds__(1024) void bscan_kernel(const int* __restrict__ bcnt,
                                                     int* __restrict__ bbase,
                                                     int* __restrict__ bcur, int NB) {
    __shared__ int s[1024];
    int t = threadIdx.x;
    int v = (t < NB) ? bcnt[t] : 0;
    s[t] = v;
    __syncthreads();
    for (int off = 1; off < 1024; off <<= 1) {
        int u = (t >= off) ? s[t - off] : 0;
        __syncthreads();
        s[t] += u;
        __syncthreads();
    }
    if (t < NB) { bbase[t] = s[t] - v; bcur[t] = s[t] - v; }
    if (t == 1023) bbase[NB] = s[1023];
}

__global__ __launch_bounds__(256) void bscatter_kernel(const int* __restrict__ src,
                                                       const int* __restrict__ dst,
                                                       const int* __restrict__ rel,
                                                       int* __restrict__ bcur,
                                                       unsigned* __restrict__ ebuf,
                                                       int m, int NB) {
    __shared__ int cnt[1024];
    for (int i = threadIdx.x; i < NB; i += 256) cnt[i] = 0;
    __syncthreads();
    int base = blockIdx.x * SC_EDGES;
    int endi = base + SC_EDGES; if (endi > m) endi = m;
    for (int i = base + threadIdx.x; i < endi; i += 256)
        atomicAdd(&cnt[dst[i] >> NPB_SHIFT], 1);
    __syncthreads();
    for (int b = threadIdx.x; b < NB; b += 256) {
        int c = cnt[b];
        if (c) cnt[b] = atomicAdd(&bcur[b], c);
    }
    __syncthreads();
    for (int i = base + threadIdx.x; i < endi; i += 256) {
        int d = dst[i];
        int bk = d >> NPB_SHIFT;
        unsigned pk = (unsigned)src[i] | ((unsigned)rel[i] << 17) |
                      ((unsigned)(d & (NPB - 1)) << 19);
        int pos = atomicAdd(&cnt[bk], 1);
        ebuf[pos] = pk;
    }
}

__global__ __launch_bounds__(256) void bfinal_kernel(const unsigned* __restrict__ ebuf,
                                                     const int* __restrict__ bbase,
                                                     int* __restrict__ rowp,
                                                     unsigned* __restrict__ csr,
                                                     int n, int m, int NB) {
    __shared__ int cnt[NPB], cur[NPB], sc[NPB];
    int b = blockIdx.x;
    int t = threadIdx.x;
    int e0 = bbase[b], e1 = bbase[b + 1];
    if (t < NPB) cnt[t] = 0;
    __syncthreads();
    for (int j = e0 + t; j < e1; j += 256)
        atomicAdd(&cnt[(ebuf[j] >> 19) & (NPB - 1)], 1);
    __syncthreads();
    int v0 = (t < NPB) ? cnt[t] : 0;
    if (t < NPB) sc[t] = v0;
    __syncthreads();
    for (int off = 1; off < NPB; off <<= 1) {
        int u = (t >= off && t < NPB) ? sc[t - off] : 0;
        __syncthreads();
        if (t < NPB) sc[t] += u;
        __syncthreads();
    }
    if (t < NPB) {
        int ex = e0 + sc[t] - v0;
        cur[t] = ex;
        int v = b * NPB + t;
        if (v < n) rowp[v] = ex;
    }
    if (b == 0 && t == 0) rowp[n] = m;
    __syncthreads();
    for (int j = e0 + t; j < e1; j += 256) {
        unsigned pk = ebuf[j];
        int dl = (pk >> 19) & (NPB - 1);
        int pos = atomicAdd(&cur[dl], 1);
        csr[pos] = (pk & 0x1FFFF) | (((pk >> 17) & 3) << 20);
    }
}

// ---------------------------------------------------------------------------
// GEMM: C[n,64] = A[n,64] @ W[64,64], 128-row tiles, 8x4 acc per thread.
// Optional fused el/er epilogue into packed el2/er2 ([node][2], slot ch).
// ---------------------------------------------------------------------------
__global__ __launch_bounds__(256) void gemm128(const float* __restrict__ A,
                                               const float* __restrict__ W,
                                               float* __restrict__ C, int n,
                                               const float* __restrict__ attn_l,
                                               const float* __restrict__ attn_r,
                                               float* __restrict__ el2,
                                               float* __restrict__ er2, int ch) {
    __shared__ __align__(16) float sW[64 * 64];
    __shared__ __align__(16) float sA[128 * 68];
    __shared__ float sAl[64], sAr[64];
    int t = threadIdx.x;
    int row0 = blockIdx.x * 128;
    for (int i = t * 4; i < 4096; i += 1024)
        *(float4*)&sW[i] = *(const float4*)&W[i];
    if (el2 && t < 64) { sAl[t] = attn_l[t]; sAr[t] = attn_r[t]; }
    int rows = n - row0; if (rows > 128) rows = 128;
    for (int i = t * 4; i < 8192; i += 1024) {
        int r = i >> 6, cc = i & 63;
        float4 v = {0.f, 0.f, 0.f, 0.f};
        if (r < rows) v = *(const float4*)&A[(size_t)(row0 + r) * 64 + cc];
        *(float4*)&sA[r * 68 + cc] = v;
    }
    __syncthreads();
    int tr = (t >> 4) * 8;
    int tc = (t & 15) * 4;
    float acc[8][4] = {};
#pragma unroll 4
    for (int k = 0; k < 64; k += 4) {
        float4 b0 = *(const float4*)&sW[(k + 0) * 64 + tc];
        float4 b1 = *(const float4*)&sW[(k + 1) * 64 + tc];
        float4 b2v = *(const float4*)&sW[(k + 2) * 64 + tc];
        float4 b3 = *(const float4*)&sW[(k + 3) * 64 + tc];
#pragma unroll
        for (int i = 0; i < 8; ++i) {
            float4 a = *(const float4*)&sA[(tr + i) * 68 + k];
            acc[i][0] += a.x * b0.x + a.y * b1.x + a.z * b2v.x + a.w * b3.x;
            acc[i][1] += a.x * b0.y + a.y * b1.y + a.z * b2v.y + a.w * b3.y;
            acc[i][2] += a.x * b0.z + a.y * b1.z + a.z * b2v.z + a.w * b3.z;
            acc[i][3] += a.x * b0.w + a.y * b1.w + a.z * b2v.w + a.w * b3.w;
        }
    }
#pragma unroll
    for (int i = 0; i < 8; ++i) {
        int r = tr + i;
        if (row0 + r < n) {
            float4 v = {acc[i][0], acc[i][1], acc[i][2], acc[i][3]};
            *(float4*)&C[(size_t)(row0 + r) * 64 + tc] = v;
        }
    }
    if (el2) {
        float pl[8], pr[8];
#pragma unroll
        for (int i = 0; i < 8; ++i) {
            float l = 0.f, r = 0.f;
#pragma unroll
            for (int j = 0; j < 4; ++j) {
                l += acc[i][j] * sAl[tc + j];
                r += acc[i][j] * sAr[tc + j];
            }
            pl[i] = l; pr[i] = r;
        }
#pragma unroll
        for (int off = 1; off < 16; off <<= 1) {
#pragma unroll
            for (int i = 0; i < 8; ++i) {
                pl[i] += __shfl_xor(pl[i], off);
                pr[i] += __shfl_xor(pr[i], off);
            }
        }
        if ((t & 15) == 0) {
#pragma unroll
            for (int i = 0; i < 8; ++i) {
                int r = row0 + tr + i;
                if (r < n) {
                    el2[(size_t)r * 2 + ch] = pl[i];
                    er2[(size_t)r * 2 + ch] = pr[i];
                }
            }
        }
    }
}

// ---------------------------------------------------------------------------
// GAT pass 1 (NCH channels), one wave per dst node.
// Lane-parallel pass computes deg/attention and stages packed edges in LDS;
// serial gather (unroll 4) reads edges from LDS, only ft rows from VMEM.
// ---------------------------------------------------------------------------
template <int NCH>
__global__ __launch_bounds__(256) void agg1_k(
        const int* __restrict__ rowp, const unsigned* __restrict__ csr,
        const float* __restrict__ filt, int fo0, int fo1,
        const float* __restrict__ el2, const float* __restrict__ er2,
        const float* __restrict__ ftA, float* __restrict__ oA,
        float* __restrict__ abA, float* __restrict__ sbA,
        const float* __restrict__ ftB, float* __restrict__ oB,
        float* __restrict__ abB, float* __restrict__ sbB, int n) {
    __shared__ unsigned sPk[4][MAXD];
    int w = (blockIdx.x * blockDim.x + threadIdx.x) >> 6;
    int lane = threadIdx.x & 63;
    int wv = threadIdx.x >> 6;
    if (w >= n) return;
    int base = rowp[w], end = rowp[w + 1];
    float fA0 = filt[fo0], fA1 = filt[fo0 + 1], fA2 = filt[fo0 + 2];
    float fB0 = 0.f, fB1 = 0.f, fB2 = 0.f;
    if (NCH == 2) { fB0 = filt[fo1]; fB1 = filt[fo1 + 1]; fB2 = filt[fo1 + 2]; }
    float2 erv = *(const float2*)&er2[(size_t)w * 2];

    // lane-parallel: stage edges, degw, unnormalized attention -> abuf, denom
    float degA = 0.f, ssA = 0.f, degB = 0.f, ssB = 0.f;
    for (int j = base + lane; j < end; j += 64) {
        unsigned pk = csr[j];
        int d = j - base;
        if (d < MAXD) sPk[wv][d] = pk;
        int s = pk & 0xFFFFF;
        int r = pk >> 20;
        float2 e2 = *(const float2*)&el2[(size_t)s * 2];
        degA += (r == 0) ? fA0 : ((r == 1) ? fA1 : fA2);
        float x = e2.x + erv.x;
        float e = __expf(x > 0.f ? x : NEG_SLOPE * x);
        abA[j] = e; ssA += e;
        if (NCH == 2) {
            degB += (r == 0) ? fB0 : ((r == 1) ? fB1 : fB2);
            float xb = e2.y + erv.y;
            float eb = __expf(xb > 0.f ? xb : NEG_SLOPE * xb);
            abB[j] = eb; ssB += eb;
        }
    }
    for (int off = 32; off; off >>= 1) {
        degA += __shfl_xor(degA, off); ssA += __shfl_xor(ssA, off);
        if (NCH == 2) { degB += __shfl_xor(degB, off); ssB += __shfl_xor(ssB, off); }
    }

    // serial gather from LDS-staged edges, unroll 4
    int deg = end - base;
    int dmax = deg < MAXD ? deg : MAXD;
    float accA = 0.f, accB = 0.f;
    int jj = 0;
    for (; jj + 4 <= dmax; jj += 4) {
        unsigned pk0 = sPk[wv][jj], pk1 = sPk[wv][jj + 1];
        unsigned pk2 = sPk[wv][jj + 2], pk3 = sPk[wv][jj + 3];
        int s0 = pk0 & 0xFFFFF, s1 = pk1 & 0xFFFFF, s2 = pk2 & 0xFFFFF, s3 = pk3 & 0xFFFFF;
        int r0 = pk0 >> 20, r1 = pk1 >> 20, r2 = pk2 >> 20, r3 = pk3 >> 20;
        float vA0 = ftA[(size_t)s0 * 64 + lane];
        float vA1 = ftA[(size_t)s1 * 64 + lane];
        float vA2 = ftA[(size_t)s2 * 64 + lane];
        float vA3 = ftA[(size_t)s3 * 64 + lane];
        float wA0 = (r0 == 0) ? fA0 : ((r0 == 1) ? fA1 : fA2);
        float wA1 = (r1 == 0) ? fA0 : ((r1 == 1) ? fA1 : fA2);
        float wA2 = (r2 == 0) ? fA0 : ((r2 == 1) ? fA1 : fA2);
        float wA3 = (r3 == 0) ? fA0 : ((r3 == 1) ? fA1 : fA2);
        accA += wA0 * vA0 + wA1 * vA1 + wA2 * vA2 + wA3 * vA3;
        if (NCH == 2) {
            float vB0 = ftB[(size_t)s0 * 64 + lane];
            float vB1 = ftB[(size_t)s1 * 64 + lane];
            float vB2 = ftB[(size_t)s2 * 64 + lane];
            float vB3 = ftB[(size_t)s3 * 64 + lane];
            float wB0 = (r0 == 0) ? fB0 : ((r0 == 1) ? fB1 : fB2);
            float wB1 = (r1 == 0) ? fB0 : ((r1 == 1) ? fB1 : fB2);
            float wB2 = (r2 == 0) ? fB0 : ((r2 == 1) ? fB1 : fB2);
            float wB3 = (r3 == 0) ? fB0 : ((r3 == 1) ? fB1 : fB2);
            accB += wB0 * vB0 + wB1 * vB1 + wB2 * vB2 + wB3 * vB3;
        }
    }
    for (; jj < dmax; ++jj) {
        unsigned pk = sPk[wv][jj];
        int s = pk & 0xFFFFF;
        int r = pk >> 20;
        float wA = (r == 0) ? fA0 : ((r == 1) ? fA1 : fA2);
        accA += wA * ftA[(size_t)s * 64 + lane];
        if (NCH == 2) {
            float wB = (r == 0) ? fB0 : ((r == 1) ? fB1 : fB2);
            accB += wB * ftB[(size_t)s * 64 + lane];
        }
    }
    for (int j = base + MAXD; j < end; ++j) {   // fallback (deg > MAXD: ~never)
        unsigned pk = csr[j];
        int s = pk & 0xFFFFF;
        int r = pk >> 20;
        float wA = (r == 0) ? fA0 : ((r == 1) ? fA1 : fA2);
        accA += wA * ftA[(size_t)s * 64 + lane];
        if (NCH == 2) {
            float wB = (r == 0) ? fB0 : ((r == 1) ? fB1 : fB2);
            accB += wB * ftB[(size_t)s * 64 + lane];
        }
    }
    float dA = degA > 0.f ? degA : 1.f;
    oA[(size_t)w * 64 + lane] = accA / dA;
    if (lane == 0) sbA[w] = (ssA > 0.f) ? 1.f / ssA : 0.f;
    if (NCH == 2) {
        float dB = degB > 0.f ? degB : 1.f;
        oB[(size_t)w * 64 + lane] = accB / dB;
        if (lane == 0) sbB[w] = (ssB > 0.f) ? 1.f / ssB : 0.f;
    }
}

// ---------------------------------------------------------------------------
// GAT pass 2 (NCH channels): stage (src, aA, aB) in LDS, then serial gather.
// ---------------------------------------------------------------------------
template <int NCH>
__global__ __launch_bounds__(256) void agg2_k(
        const int* __restrict__ rowp, const unsigned* __restrict__ csr,
        const float* __restrict__ ftA, const float* __restrict__ abA,
        const float* __restrict__ sbA, float* __restrict__ oA,
        const float* __restrict__ ftB, const float* __restrict__ abB,
        const float* __restrict__ sbB, float* __restrict__ oB, int n) {
    __shared__ unsigned sPk[4][MAXD];
    __shared__ float sWa[4][MAXD];
    __shared__ float sWb[4][MAXD];
    int w = (blockIdx.x * blockDim.x + threadIdx.x) >> 6;
    int lane = threadIdx.x & 63;
    int wv = threadIdx.x >> 6;
    if (w >= n) return;
    int base = rowp[w], end = rowp[w + 1];
    float invA = sbA[w];
    float invB = (NCH == 2) ? sbB[w] : 0.f;

    // lane-parallel staging
    for (int j = base + lane; j < end; j += 64) {
        int d = j - base;
        if (d < MAXD) {
            sPk[wv][d] = csr[j];
            sWa[wv][d] = abA[j];
            if (NCH == 2) sWb[wv][d] = abB[j];
        }
    }

    int deg = end - base;
    int dmax = deg < MAXD ? deg : MAXD;
    float accA = 0.f, accB = 0.f;
    int jj = 0;
    for (; jj + 4 <= dmax; jj += 4) {
        int s0 = sPk[wv][jj] & 0xFFFFF, s1 = sPk[wv][jj + 1] & 0xFFFFF;
        int s2 = sPk[wv][jj + 2] & 0xFFFFF, s3 = sPk[wv][jj + 3] & 0xFFFFF;
        float a0 = sWa[wv][jj], a1 = sWa[wv][jj + 1];
        float a2 = sWa[wv][jj + 2], a3 = sWa[wv][jj + 3];
        float vA0 = ftA[(size_t)s0 * 64 + lane];
        float vA1 = ftA[(size_t)s1 * 64 + lane];
        float vA2 = ftA[(size_t)s2 * 64 + lane];
        float vA3 = ftA[(size_t)s3 * 64 + lane];
        accA += a0 * vA0 + a1 * vA1 + a2 * vA2 + a3 * vA3;
        if (NCH == 2) {
            float b0 = sWb[wv][jj], b1 = sWb[wv][jj + 1];
            float b2 = sWb[wv][jj + 2], b3 = sWb[wv][jj + 3];
            float vB0 = ftB[(size_t)s0 * 64 + lane];
            float vB1 = ftB[(size_t)s1 * 64 + lane];
            float vB2 = ftB[(size_t)s2 * 64 + lane];
            float vB3 = ftB[(size_t)s3 * 64 + lane];
            accB += b0 * vB0 + b1 * vB1 + b2 * vB2 + b3 * vB3;
        }
    }
    for (; jj < dmax; ++jj) {
        int s = sPk[wv][jj] & 0xFFFFF;
        accA += sWa[wv][jj] * ftA[(size_t)s * 64 + lane];
        if (NCH == 2) accB += sWb[wv][jj] * ftB[(size_t)s * 64 + lane];
    }
    for (int j = base + MAXD; j < end; ++j) {   // fallback
        unsigned pk = csr[j];
        int s = pk & 0xFFFFF;
        accA += abA[j] * ftA[(size_t)s * 64 + lane];
        if (NCH == 2) accB += abB[j] * ftB[(size_t)s * 64 + lane];
    }
    oA[(size_t)w * 64 + lane] = accA * invA;
    if (NCH == 2) oB[(size_t)w * 64 + lane] = accB * invB;
}

// ---------------------------------------------------------------------------
// Fused final: out = b2 + (lw0*A0 + lw1*A1) @ W2
// ---------------------------------------------------------------------------
__global__ __launch_bounds__(256) void gemm_out2(const float* __restrict__ A0,
                                                 const float* __restrict__ A1,
                                                 const float* __restrict__ W2,
                                                 const float* __restrict__ b2,
                                                 const float* __restrict__ lin_w,
                                                 float* __restrict__ out, int n) {
    __shared__ __align__(16) float sW[64 * 50];
    __shared__ __align__(16) float sA[64 * 68];
    int t = threadIdx.x;
    int row0 = blockIdx.x * 64;
    float lw0 = lin_w[0], lw1 = lin_w[1];
    for (int i = t; i < 64 * 50; i += 256) sW[i] = W2[i];
    int rows = n - row0; if (rows > 64) rows = 64;
    for (int i = t * 4; i < 4096; i += 1024) {
        int r = i >> 6, cc = i & 63;
        float4 v = {0.f, 0.f, 0.f, 0.f};
        if (r < rows) {
            float4 a = *(const float4*)&A0[(size_t)(row0 + r) * 64 + cc];
            float4 b = *(const float4*)&A1[(size_t)(row0 + r) * 64 + cc];
            v.x = lw0 * a.x + lw1 * b.x; v.y = lw0 * a.y + lw1 * b.y;
            v.z = lw0 * a.z + lw1 * b.z; v.w = lw0 * a.w + lw1 * b.w;
        }
        *(float4*)&sA[r * 68 + cc] = v;
    }
    __syncthreads();
    for (int i = t; i < 64 * 50; i += 256) {
        int r = i / 50, col = i - r * 50;
        if (row0 + r >= n) continue;
        float acc = 0.f;
#pragma unroll
        for (int k = 0; k < 64; ++k) acc += sA[r * 68 + k] * sW[k * 50 + col];
        out[(size_t)(row0 + r) * 50 + col] = b2[col] + acc;
    }
}

// per-channel fallback
__global__ __launch_bounds__(256) void gemm_out(const float* __restrict__ A,
                                                const float* __restrict__ W2,
                                                const float* __restrict__ b2,
                                                const float* __restrict__ lin_w,
                                                float* __restrict__ out, int n, int c) {
    __shared__ __align__(16) float sW[64 * 50];
    __shared__ __align__(16) float sA[64 * 68];
    int t = threadIdx.x;
    int row0 = blockIdx.x * 64;
    for (int i = t; i < 64 * 50; i += 256) sW[i] = W2[i];
    int rows = n - row0; if (rows > 64) rows = 64;
    for (int i = t * 4; i < 4096; i += 1024) {
        int r = i >> 6, cc = i & 63;
        float4 v = {0.f, 0.f, 0.f, 0.f};
        if (r < rows) v = *(const float4*)&A[(size_t)(row0 + r) * 64 + cc];
        *(float4*)&sA[r * 68 + cc] = v;
    }
    float lw = lin_w[c];
    __syncthreads();
    for (int i = t; i < 64 * 50; i += 256) {
        int r = i / 50, col = i - r * 50;
        if (row0 + r >= n) continue;
        float acc = 0.f;
#pragma unroll
        for (int k = 0; k < 64; ++k) acc += sA[r * 68 + k] * sW[k * 50 + col];
        size_t o = (size_t)(row0 + r) * 50 + col;
        float base = (c == 0) ? b2[col] : out[o];
        out[o] = base + lw * acc;
    }
}

// ---------------------------------------------------------------------------
extern "C" void kernel_launch(void* const* d_in, const int* in_sizes, int n_in,
                              void* d_out, int out_size, void* d_ws, size_t ws_size,
                              hipStream_t stream) {
    const float* h      = (const float*)d_in[0];
    const float* params = (const float*)d_in[1];
    const float* gt_w   = (const float*)d_in[2];
    const float* fc_w   = (const float*)d_in[3];
    const float* attn_l = (const float*)d_in[4];
    const float* attn_r = (const float*)d_in[5];
    const float* lin_w  = (const float*)d_in[6];
    const float* W2     = (const float*)d_in[7];
    const float* b2     = (const float*)d_in[8];
    const int*   src    = (const int*)d_in[9];
    const int*   dst    = (const int*)d_in[10];
    const int*   rel    = (const int*)d_in[11];

    const int n = in_sizes[0] / 64;      // 100000 nodes
    const int m = in_sizes[9];           // 1.8M edges
    const int C = 2, L = 2;
    float* out = (float*)d_out;

    char* base = (char*)d_ws;
    size_t off = 0;
    auto alloc = [&](size_t bytes) -> char* {
        char* p = base + off;
        off = (off + bytes + 255) & ~(size_t)255;
        return p;
    };
    const int NB = (n + NPB - 1) >> NPB_SHIFT;
    const int nchunks = (m + SC_EDGES - 1) / SC_EDGES;
    // common
    float*    filt  = (float*)alloc(L * C * 3 * sizeof(float));
    float*    Wc    = (float*)alloc((size_t)C * 64 * 64 * 4);
    int*      bcnt  = (int*)alloc((size_t)NB * 4);
    int*      bbase = (int*)alloc((size_t)(NB + 1) * 4);
    int*      bcur  = (int*)alloc((size_t)NB * 4);
    int*      rowp  = (int*)alloc((size_t)(n + 1) * 4);
    unsigned* ebuf  = (unsigned*)alloc((size_t)m * 4);
    unsigned* csr   = (unsigned*)alloc((size_t)m * 4);
    float*    el2   = (float*)alloc((size_t)n * 2 * 4);
    float*    er2   = (float*)alloc((size_t)n * 2 * 4);
    // channel A
    float*    sbA  = (float*)alloc((size_t)n * 4);
    float*    abA  = (float*)alloc((size_t)m * 4);
    float*    A0   = (float*)alloc((size_t)n * 64 * 4);
    float*    B0   = (float*)alloc((size_t)n * 64 * 4);
    float*    C0   = (float*)alloc((size_t)n * 64 * 4);
    // channel B
    float*    sbB  = (float*)alloc((size_t)n * 4);
    float*    abB  = (float*)alloc((size_t)m * 4);
    float*    A1   = (float*)alloc((size_t)n * 64 * 4);
    float*    B1   = (float*)alloc((size_t)n * 64 * 4);
    float*    C1   = (float*)alloc((size_t)n * 64 * 4);
    bool dual = (off <= ws_size);

    // ---- CSR build ----
    hipMemsetAsync(bcnt, 0, (size_t)NB * 4, stream);
    mkfilt<<<1, 64, 0, stream>>>(gt_w, filt, L * C);
    combw_kernel<<<C, 256, 0, stream>>>(params, fc_w, Wc);
    bcount_kernel<<<nchunks, 256, 0, stream>>>(dst, bcnt, m, NB);
    bscan_kernel<<<1, 1024, 0, stream>>>(bcnt, bbase, bcur, NB);
    bscatter_kernel<<<nchunks, 256, 0, stream>>>(src, dst, rel, bcur, ebuf, m, NB);
    bfinal_kernel<<<NB, 256, 0, stream>>>(ebuf, bbase, rowp, csr, n, m, NB);

    const int gB = (n + 127) / 128;
    const int gOut = (n + 63) / 64;
    const int waveBlocks = (n + 3) / 4;

    if (dual) {
        for (int l = 0; l < L; ++l) {
            if (l == 0) {
                gemm128<<<gB, 256, 0, stream>>>(h, Wc, B0, n, attn_l, attn_r, el2, er2, 0);
                gemm128<<<gB, 256, 0, stream>>>(h, Wc + 64 * 64, B1, n,
                                                attn_l, attn_r, el2, er2, 1);
            } else {
                gemm128<<<gB, 256, 0, stream>>>(A0, fc_w, B0, n, attn_l, attn_r, el2, er2, 0);
                gemm128<<<gB, 256, 0, stream>>>(A1, fc_w, B1, n, attn_l, attn_r, el2, er2, 1);
            }
            int fo0 = (l * C + 0) * 3, fo1 = (l * C + 1) * 3;
            agg1_k<2><<<waveBlocks, 256, 0, stream>>>(rowp, csr, filt, fo0, fo1, el2, er2,
                                                      B0, C0, abA, sbA,
                                                      B1, C1, abB, sbB, n);
            agg2_k<2><<<waveBlocks, 256, 0, stream>>>(rowp, csr,
                                                      C0, abA, sbA, A0,
                                                      C1, abB, sbB, A1, n);
        }
        gemm_out2<<<gOut, 256, 0, stream>>>(A0, A1, W2, b2, lin_w, out, n);
    } else {
        for (int c = 0; c < C; ++c) {
            for (int l = 0; l < L; ++l) {
                const float* Ain = (l == 0) ? h : A0;
                const float* Win = (l == 0) ? (Wc + (size_t)c * 64 * 64) : fc_w;
                gemm128<<<gB, 256, 0, stream>>>(Ain, Win, B0, n,
                                                attn_l, attn_r, el2, er2, 0);
                int fo = (l * C + c) * 3;
                agg1_k<1><<<waveBlocks, 256, 0, stream>>>(rowp, csr, filt, fo, fo, el2, er2,
                                                          B0, C0, abA, sbA,
                                                          nullptr, nullptr, nullptr, nullptr, n);
                agg2_k<1><<<waveBlocks, 256, 0, stream>>>(rowp, csr,
                                                          C0, abA, sbA, A0,
                                                          nullptr, nullptr, nullptr, nullptr, n);
            }
            gemm_out<<<gOut, 256, 0, stream>>>(A0, W2, b2, lin_w, out, n, c);
        }
    }
}

// Round 7
// 769.911 us; speedup vs baseline: 1.2434x; 1.0363x over previous
//
#include <hip/hip_runtime.h>
#include <hip/hip_bf16.h>
#include <math.h>

#define NEG_SLOPE 0.2f
#define NPB_SHIFT 7
#define NPB 128          // nodes per bucket
#define SC_EDGES 16384   // edges per bscatter block
#define MAXD 128         // per-node edges staged in LDS

// ---------------------------------------------------------------------------
// filt[l][c][r] = softmax_r(gt_w[l][c][:])
// ---------------------------------------------------------------------------
__global__ void mkfilt(const float* __restrict__ gt_w, float* __restrict__ filt,
                       int rows) {
    int i = threadIdx.x;
    if (i < rows) {
        const float* g = gt_w + i * 3;
        float m = fmaxf(g[0], fmaxf(g[1], g[2]));
        float e0 = __expf(g[0] - m), e1 = __expf(g[1] - m), e2 = __expf(g[2] - m);
        float s = e0 + e1 + e2;
        filt[i * 3 + 0] = e0 / s;
        filt[i * 3 + 1] = e1 / s;
        filt[i * 3 + 2] = e2 / s;
    }
}

// ---------------------------------------------------------------------------
// Wc[c] = params[c] @ fc_w
// ---------------------------------------------------------------------------
__global__ __launch_bounds__(256) void combw_kernel(const float* __restrict__ params,
                                                    const float* __restrict__ fc_w,
                                                    float* __restrict__ Wc) {
    __shared__ __align__(16) float sP[64 * 64], sF[64 * 64];
    const float* P = params + (size_t)blockIdx.x * 64 * 64;
    int t = threadIdx.x;
    for (int i = t * 4; i < 4096; i += 1024) {
        *(float4*)&sP[i] = *(const float4*)&P[i];
        *(float4*)&sF[i] = *(const float4*)&fc_w[i];
    }
    __syncthreads();
    float* O = Wc + (size_t)blockIdx.x * 64 * 64;
    for (int i = t; i < 4096; i += 256) {
        int r = i >> 6, c = i & 63;
        float acc = 0.f;
#pragma unroll
        for (int k = 0; k < 64; ++k) acc += sP[r * 64 + k] * sF[k * 64 + c];
        O[i] = acc;
    }
}

// ---------------------------------------------------------------------------
// Bucketed CSR build (unchanged from R6)
// ---------------------------------------------------------------------------
__global__ __launch_bounds__(256) void bcount_kernel(const int* __restrict__ dst,
                                                     int* __restrict__ bcnt, int m, int NB) {
    __shared__ int h[1024];
    for (int i = threadIdx.x; i < NB; i += 256) h[i] = 0;
    __syncthreads();
    int base = blockIdx.x * SC_EDGES;
    int endi = base + SC_EDGES; if (endi > m) endi = m;
    for (int i = base + threadIdx.x; i < endi; i += 256)
        atomicAdd(&h[dst[i] >> NPB_SHIFT], 1);
    __syncthreads();
    for (int i = threadIdx.x; i < NB; i += 256)
        if (h[i]) atomicAdd(&bcnt[i], h[i]);
}

__global__ __launch_bounds__(1024) void bscan_kernel(const int* __restrict__ bcnt,
                                                     int* __restrict__ bbase,
                                                     int* __restrict__ bcur, int NB) {
    __shared__ int s[1024];
    int t = threadIdx.x;
    int v = (t < NB) ? bcnt[t] : 0;
    s[t] = v;
    __syncthreads();
    for (int off = 1; off < 1024; off <<= 1) {
        int u = (t >= off) ? s[t - off] : 0;
        __syncthreads();
        s[t] += u;
        __syncthreads();
    }
    if (t < NB) { bbase[t] = s[t] - v; bcur[t] = s[t] - v; }
    if (t == 1023) bbase[NB] = s[1023];
}

__global__ __launch_bounds__(256) void bscatter_kernel(const int* __restrict__ src,
                                                       const int* __restrict__ dst,
                                                       const int* __restrict__ rel,
                                                       int* __restrict__ bcur,
                                                       unsigned* __restrict__ ebuf,
                                                       int m, int NB) {
    __shared__ int cnt[1024];
    for (int i = threadIdx.x; i < NB; i += 256) cnt[i] = 0;
    __syncthreads();
    int base = blockIdx.x * SC_EDGES;
    int endi = base + SC_EDGES; if (endi > m) endi = m;
    for (int i = base + threadIdx.x; i < endi; i += 256)
        atomicAdd(&cnt[dst[i] >> NPB_SHIFT], 1);
    __syncthreads();
    for (int b = threadIdx.x; b < NB; b += 256) {
        int c = cnt[b];
        if (c) cnt[b] = atomicAdd(&bcur[b], c);
    }
    __syncthreads();
    for (int i = base + threadIdx.x; i < endi; i += 256) {
        int d = dst[i];
        int bk = d >> NPB_SHIFT;
        unsigned pk = (unsigned)src[i] | ((unsigned)rel[i] << 17) |
                      ((unsigned)(d & (NPB - 1)) << 19);
        int pos = atomicAdd(&cnt[bk], 1);
        ebuf[pos] = pk;
    }
}

__global__ __launch_bounds__(256) void bfinal_kernel(const unsigned* __restrict__ ebuf,
                                                     const int* __restrict__ bbase,
                                                     int* __restrict__ rowp,
                                                     unsigned* __restrict__ csr,
                                                     int n, int m, int NB) {
    __shared__ int cnt[NPB], cur[NPB], sc[NPB];
    int b = blockIdx.x;
    int t = threadIdx.x;
    int e0 = bbase[b], e1 = bbase[b + 1];
    if (t < NPB) cnt[t] = 0;
    __syncthreads();
    for (int j = e0 + t; j < e1; j += 256)
        atomicAdd(&cnt[(ebuf[j] >> 19) & (NPB - 1)], 1);
    __syncthreads();
    int v0 = (t < NPB) ? cnt[t] : 0;
    if (t < NPB) sc[t] = v0;
    __syncthreads();
    for (int off = 1; off < NPB; off <<= 1) {
        int u = (t >= off && t < NPB) ? sc[t - off] : 0;
        __syncthreads();
        if (t < NPB) sc[t] += u;
        __syncthreads();
    }
    if (t < NPB) {
        int ex = e0 + sc[t] - v0;
        cur[t] = ex;
        int v = b * NPB + t;
        if (v < n) rowp[v] = ex;
    }
    if (b == 0 && t == 0) rowp[n] = m;
    __syncthreads();
    for (int j = e0 + t; j < e1; j += 256) {
        unsigned pk = ebuf[j];
        int dl = (pk >> 19) & (NPB - 1);
        int pos = atomicAdd(&cur[dl], 1);
        csr[pos] = (pk & 0x1FFFF) | (((pk >> 17) & 3) << 20);
    }
}

// ---------------------------------------------------------------------------
// Layer-0 dual GEMM: OAB[r][d] = ( (h@Wc0)[r][d], (h@Wc1)[r][d] )  interleaved
// + fused el/er for both channels into el2/er2 (float2 per node).
// ---------------------------------------------------------------------------
__global__ __launch_bounds__(256) void gemm_l0(const float* __restrict__ A,
                                               const float* __restrict__ Wc, // [2][64][64]
                                               float2* __restrict__ OAB, int n,
                                               const float* __restrict__ attn_l,
                                               const float* __restrict__ attn_r,
                                               float2* __restrict__ el2,
                                               float2* __restrict__ er2) {
    __shared__ __align__(16) float sW[2][64 * 64];
    __shared__ __align__(16) float sA[64 * 68];
    __shared__ float sAl[64], sAr[64];
    int t = threadIdx.x;
    int row0 = blockIdx.x * 64;
    for (int i = t * 4; i < 8192; i += 1024)
        *(float4*)&sW[0][i] = *(const float4*)&Wc[i];
    if (t < 64) { sAl[t] = attn_l[t]; sAr[t] = attn_r[t]; }
    int rows = n - row0; if (rows > 64) rows = 64;
    for (int i = t * 4; i < 4096; i += 1024) {
        int r = i >> 6, c = i & 63;
        float4 v = {0.f, 0.f, 0.f, 0.f};
        if (r < rows) v = *(const float4*)&A[(size_t)(row0 + r) * 64 + c];
        *(float4*)&sA[r * 68 + c] = v;
    }
    __syncthreads();
    int tr = (t >> 4) * 4, tc = (t & 15) * 4;
    float accA[4][4] = {}, accB[4][4] = {};
#pragma unroll 4
    for (int k = 0; k < 64; k += 4) {
        float4 av[4];
#pragma unroll
        for (int i = 0; i < 4; ++i) av[i] = *(const float4*)&sA[(tr + i) * 68 + k];
#pragma unroll
        for (int kk = 0; kk < 4; ++kk) {
            float4 bA = *(const float4*)&sW[0][(k + kk) * 64 + tc];
            float4 bB = *(const float4*)&sW[1][(k + kk) * 64 + tc];
#pragma unroll
            for (int i = 0; i < 4; ++i) {
                float a = (&av[i].x)[kk];
                accA[i][0] += a * bA.x; accA[i][1] += a * bA.y;
                accA[i][2] += a * bA.z; accA[i][3] += a * bA.w;
                accB[i][0] += a * bB.x; accB[i][1] += a * bB.y;
                accB[i][2] += a * bB.z; accB[i][3] += a * bB.w;
            }
        }
    }
#pragma unroll
    for (int i = 0; i < 4; ++i) {
        int r = row0 + tr + i;
        if (r < n) {
            float4 v0 = {accA[i][0], accB[i][0], accA[i][1], accB[i][1]};
            float4 v1 = {accA[i][2], accB[i][2], accA[i][3], accB[i][3]};
            float* o = (float*)&OAB[(size_t)r * 64 + tc];
            *(float4*)o = v0;
            *(float4*)(o + 4) = v1;
        }
    }
    // fused el/er (both channels)
    float plA[4], prA[4], plB[4], prB[4];
#pragma unroll
    for (int i = 0; i < 4; ++i) {
        float la = 0.f, ra = 0.f, lb = 0.f, rb = 0.f;
#pragma unroll
        for (int j = 0; j < 4; ++j) {
            la += accA[i][j] * sAl[tc + j]; ra += accA[i][j] * sAr[tc + j];
            lb += accB[i][j] * sAl[tc + j]; rb += accB[i][j] * sAr[tc + j];
        }
        plA[i] = la; prA[i] = ra; plB[i] = lb; prB[i] = rb;
    }
#pragma unroll
    for (int off = 1; off < 16; off <<= 1) {
#pragma unroll
        for (int i = 0; i < 4; ++i) {
            plA[i] += __shfl_xor(plA[i], off); prA[i] += __shfl_xor(prA[i], off);
            plB[i] += __shfl_xor(plB[i], off); prB[i] += __shfl_xor(prB[i], off);
        }
    }
    if ((t & 15) == 0) {
#pragma unroll
        for (int i = 0; i < 4; ++i) {
            int r = row0 + tr + i;
            if (r < n) {
                el2[r] = make_float2(plA[i], plB[i]);
                er2[r] = make_float2(prA[i], prB[i]);
            }
        }
    }
}

// ---------------------------------------------------------------------------
// Layer-1 dual GEMM: in = AAB (interleaved), W = fc_w (shared by channels).
// ---------------------------------------------------------------------------
__global__ __launch_bounds__(256) void gemm_l1(const float2* __restrict__ AAB,
                                               const float* __restrict__ W,
                                               float2* __restrict__ OAB, int n,
                                               const float* __restrict__ attn_l,
                                               const float* __restrict__ attn_r,
                                               float2* __restrict__ el2,
                                               float2* __restrict__ er2) {
    __shared__ __align__(16) float sW[64 * 64];
    __shared__ __align__(16) float sAx[64 * 68];
    __shared__ __align__(16) float sAy[64 * 68];
    __shared__ float sAl[64], sAr[64];
    int t = threadIdx.x;
    int row0 = blockIdx.x * 64;
    for (int i = t * 4; i < 4096; i += 1024)
        *(float4*)&sW[i] = *(const float4*)&W[i];
    if (t < 64) { sAl[t] = attn_l[t]; sAr[t] = attn_r[t]; }
    int rows = n - row0; if (rows > 64) rows = 64;
    for (int i = t * 4; i < 8192; i += 1024) {      // 64 rows x 128 floats
        int r = i >> 7, c2 = i & 127;               // c2 = dim*2 (+ch)
        float4 v = {0.f, 0.f, 0.f, 0.f};
        if (r < rows) v = *(const float4*)((const float*)&AAB[(size_t)(row0 + r) * 64] + c2);
        int dim = c2 >> 1;
        sAx[r * 68 + dim] = v.x; sAy[r * 68 + dim] = v.y;
        sAx[r * 68 + dim + 1] = v.z; sAy[r * 68 + dim + 1] = v.w;
    }
    __syncthreads();
    int tr = (t >> 4) * 4, tc = (t & 15) * 4;
    float accA[4][4] = {}, accB[4][4] = {};
#pragma unroll 4
    for (int k = 0; k < 64; k += 4) {
        float4 ax[4], ay[4];
#pragma unroll
        for (int i = 0; i < 4; ++i) {
            ax[i] = *(const float4*)&sAx[(tr + i) * 68 + k];
            ay[i] = *(const float4*)&sAy[(tr + i) * 68 + k];
        }
#pragma unroll
        for (int kk = 0; kk < 4; ++kk) {
            float4 b = *(const float4*)&sW[(k + kk) * 64 + tc];
#pragma unroll
            for (int i = 0; i < 4; ++i) {
                float a = (&ax[i].x)[kk];
                float c = (&ay[i].x)[kk];
                accA[i][0] += a * b.x; accA[i][1] += a * b.y;
                accA[i][2] += a * b.z; accA[i][3] += a * b.w;
                accB[i][0] += c * b.x; accB[i][1] += c * b.y;
                accB[i][2] += c * b.z; accB[i][3] += c * b.w;
            }
        }
    }
#pragma unroll
    for (int i = 0; i < 4; ++i) {
        int r = row0 + tr + i;
        if (r < n) {
            float4 v0 = {accA[i][0], accB[i][0], accA[i][1], accB[i][1]};
            float4 v1 = {accA[i][2], accB[i][2], accA[i][3], accB[i][3]};
            float* o = (float*)&OAB[(size_t)r * 64 + tc];
            *(float4*)o = v0;
            *(float4*)(o + 4) = v1;
        }
    }
    float plA[4], prA[4], plB[4], prB[4];
#pragma unroll
    for (int i = 0; i < 4; ++i) {
        float la = 0.f, ra = 0.f, lb = 0.f, rb = 0.f;
#pragma unroll
        for (int j = 0; j < 4; ++j) {
            la += accA[i][j] * sAl[tc + j]; ra += accA[i][j] * sAr[tc + j];
            lb += accB[i][j] * sAl[tc + j]; rb += accB[i][j] * sAr[tc + j];
        }
        plA[i] = la; prA[i] = ra; plB[i] = lb; prB[i] = rb;
    }
#pragma unroll
    for (int off = 1; off < 16; off <<= 1) {
#pragma unroll
        for (int i = 0; i < 4; ++i) {
            plA[i] += __shfl_xor(plA[i], off); prA[i] += __shfl_xor(prA[i], off);
            plB[i] += __shfl_xor(plB[i], off); prB[i] += __shfl_xor(prB[i], off);
        }
    }
    if ((t & 15) == 0) {
#pragma unroll
        for (int i = 0; i < 4; ++i) {
            int r = row0 + tr + i;
            if (r < n) {
                el2[r] = make_float2(plA[i], plB[i]);
                er2[r] = make_float2(prA[i], prB[i]);
            }
        }
    }
}

// ---------------------------------------------------------------------------
// GAT pass 1, dual channel, interleaved float2 gather. One wave per dst node.
// ---------------------------------------------------------------------------
__global__ __launch_bounds__(256) void agg1_ab(
        const int* __restrict__ rowp, const unsigned* __restrict__ csr,
        const float* __restrict__ filt, int fo0, int fo1,
        const float2* __restrict__ el2, const float2* __restrict__ er2,
        const float2* __restrict__ ftAB, float2* __restrict__ oAB,
        float2* __restrict__ sbAB, int n) {
    __shared__ unsigned sPk[4][MAXD];
    int w = (blockIdx.x * blockDim.x + threadIdx.x) >> 6;
    int lane = threadIdx.x & 63;
    int wv = threadIdx.x >> 6;
    if (w >= n) return;
    int base = rowp[w], end = rowp[w + 1];
    float fA0 = filt[fo0], fA1 = filt[fo0 + 1], fA2 = filt[fo0 + 2];
    float fB0 = filt[fo1], fB1 = filt[fo1 + 1], fB2 = filt[fo1 + 2];
    float2 erv = er2[w];

    // lane-parallel: stage edges, degw + softmax denom (no max shift: exact)
    float degA = 0.f, ssA = 0.f, degB = 0.f, ssB = 0.f;
    for (int j = base + lane; j < end; j += 64) {
        unsigned pk = csr[j];
        int d = j - base;
        if (d < MAXD) sPk[wv][d] = pk;
        int s = pk & 0xFFFFF;
        int r = pk >> 20;
        float2 e2 = el2[s];
        degA += (r == 0) ? fA0 : ((r == 1) ? fA1 : fA2);
        degB += (r == 0) ? fB0 : ((r == 1) ? fB1 : fB2);
        float xA = e2.x + erv.x;
        ssA += __expf(xA > 0.f ? xA : NEG_SLOPE * xA);
        float xB = e2.y + erv.y;
        ssB += __expf(xB > 0.f ? xB : NEG_SLOPE * xB);
    }
    for (int off = 32; off; off >>= 1) {
        degA += __shfl_xor(degA, off); ssA += __shfl_xor(ssA, off);
        degB += __shfl_xor(degB, off); ssB += __shfl_xor(ssB, off);
    }

    // serial gather: one float2 (both channels) per edge, unroll 4
    int deg = end - base;
    int dmax = deg < MAXD ? deg : MAXD;
    float accA = 0.f, accB = 0.f;
    int jj = 0;
    for (; jj + 4 <= dmax; jj += 4) {
        unsigned pk0 = sPk[wv][jj], pk1 = sPk[wv][jj + 1];
        unsigned pk2 = sPk[wv][jj + 2], pk3 = sPk[wv][jj + 3];
        int s0 = pk0 & 0xFFFFF, s1 = pk1 & 0xFFFFF, s2 = pk2 & 0xFFFFF, s3 = pk3 & 0xFFFFF;
        int r0 = pk0 >> 20, r1 = pk1 >> 20, r2 = pk2 >> 20, r3 = pk3 >> 20;
        float2 v0 = ftAB[(size_t)s0 * 64 + lane];
        float2 v1 = ftAB[(size_t)s1 * 64 + lane];
        float2 v2 = ftAB[(size_t)s2 * 64 + lane];
        float2 v3 = ftAB[(size_t)s3 * 64 + lane];
        float wA0 = (r0 == 0) ? fA0 : ((r0 == 1) ? fA1 : fA2);
        float wA1 = (r1 == 0) ? fA0 : ((r1 == 1) ? fA1 : fA2);
        float wA2 = (r2 == 0) ? fA0 : ((r2 == 1) ? fA1 : fA2);
        float wA3 = (r3 == 0) ? fA0 : ((r3 == 1) ? fA1 : fA2);
        float wB0 = (r0 == 0) ? fB0 : ((r0 == 1) ? fB1 : fB2);
        float wB1 = (r1 == 0) ? fB0 : ((r1 == 1) ? fB1 : fB2);
        float wB2 = (r2 == 0) ? fB0 : ((r2 == 1) ? fB1 : fB2);
        float wB3 = (r3 == 0) ? fB0 : ((r3 == 1) ? fB1 : fB2);
        accA += wA0 * v0.x + wA1 * v1.x + wA2 * v2.x + wA3 * v3.x;
        accB += wB0 * v0.y + wB1 * v1.y + wB2 * v2.y + wB3 * v3.y;
    }
    for (; jj < dmax; ++jj) {
        unsigned pk = sPk[wv][jj];
        int s = pk & 0xFFFFF;
        int r = pk >> 20;
        float2 v = ftAB[(size_t)s * 64 + lane];
        accA += ((r == 0) ? fA0 : ((r == 1) ? fA1 : fA2)) * v.x;
        accB += ((r == 0) ? fB0 : ((r == 1) ? fB1 : fB2)) * v.y;
    }
    for (int j = base + MAXD; j < end; ++j) {   // deg > MAXD fallback (~never)
        unsigned pk = csr[j];
        int s = pk & 0xFFFFF;
        int r = pk >> 20;
        float2 v = ftAB[(size_t)s * 64 + lane];
        accA += ((r == 0) ? fA0 : ((r == 1) ? fA1 : fA2)) * v.x;
        accB += ((r == 0) ? fB0 : ((r == 1) ? fB1 : fB2)) * v.y;
    }
    float dA = degA > 0.f ? degA : 1.f;
    float dB = degB > 0.f ? degB : 1.f;
    oAB[(size_t)w * 64 + lane] = make_float2(accA / dA, accB / dB);
    if (lane == 0)
        sbAB[w] = make_float2(ssA > 0.f ? 1.f / ssA : 0.f,
                              ssB > 0.f ? 1.f / ssB : 0.f);
}

// ---------------------------------------------------------------------------
// GAT pass 2, dual channel: recompute attention e from el2 (L2-resident),
// stage (pk, eA, eB) in LDS, serial float2 gather.
// ---------------------------------------------------------------------------
__global__ __launch_bounds__(256) void agg2_ab(
        const int* __restrict__ rowp, const unsigned* __restrict__ csr,
        const float2* __restrict__ el2, const float2* __restrict__ er2,
        const float2* __restrict__ sbAB,
        const float2* __restrict__ ftAB, float2* __restrict__ oAB, int n) {
    __shared__ unsigned sPk[4][MAXD];
    __shared__ float sEa[4][MAXD];
    __shared__ float sEb[4][MAXD];
    int w = (blockIdx.x * blockDim.x + threadIdx.x) >> 6;
    int lane = threadIdx.x & 63;
    int wv = threadIdx.x >> 6;
    if (w >= n) return;
    int base = rowp[w], end = rowp[w + 1];
    float2 erv = er2[w];
    float2 inv = sbAB[w];

    for (int j = base + lane; j < end; j += 64) {
        unsigned pk = csr[j];
        int d = j - base;
        int s = pk & 0xFFFFF;
        float2 e2 = el2[s];
        float xA = e2.x + erv.x;
        float xB = e2.y + erv.y;
        float eA = __expf(xA > 0.f ? xA : NEG_SLOPE * xA);
        float eB = __expf(xB > 0.f ? xB : NEG_SLOPE * xB);
        if (d < MAXD) {
            sPk[wv][d] = pk;
            sEa[wv][d] = eA;
            sEb[wv][d] = eB;
        }
    }

    int deg = end - base;
    int dmax = deg < MAXD ? deg : MAXD;
    float accA = 0.f, accB = 0.f;
    int jj = 0;
    for (; jj + 4 <= dmax; jj += 4) {
        int s0 = sPk[wv][jj] & 0xFFFFF, s1 = sPk[wv][jj + 1] & 0xFFFFF;
        int s2 = sPk[wv][jj + 2] & 0xFFFFF, s3 = sPk[wv][jj + 3] & 0xFFFFF;
        float a0 = sEa[wv][jj], a1 = sEa[wv][jj + 1];
        float a2 = sEa[wv][jj + 2], a3 = sEa[wv][jj + 3];
        float b0 = sEb[wv][jj], b1 = sEb[wv][jj + 1];
        float b2 = sEb[wv][jj + 2], b3 = sEb[wv][jj + 3];
        float2 v0 = ftAB[(size_t)s0 * 64 + lane];
        float2 v1 = ftAB[(size_t)s1 * 64 + lane];
        float2 v2 = ftAB[(size_t)s2 * 64 + lane];
        float2 v3 = ftAB[(size_t)s3 * 64 + lane];
        accA += a0 * v0.x + a1 * v1.x + a2 * v2.x + a3 * v3.x;
        accB += b0 * v0.y + b1 * v1.y + b2 * v2.y + b3 * v3.y;
    }
    for (; jj < dmax; ++jj) {
        int s = sPk[wv][jj] & 0xFFFFF;
        float2 v = ftAB[(size_t)s * 64 + lane];
        accA += sEa[wv][jj] * v.x;
        accB += sEb[wv][jj] * v.y;
    }
    for (int j = base + MAXD; j < end; ++j) {   // fallback
        unsigned pk = csr[j];
        int s = pk & 0xFFFFF;
        float2 e2 = el2[s];
        float xA = e2.x + erv.x;
        float xB = e2.y + erv.y;
        float2 v = ftAB[(size_t)s * 64 + lane];
        accA += __expf(xA > 0.f ? xA : NEG_SLOPE * xA) * v.x;
        accB += __expf(xB > 0.f ? xB : NEG_SLOPE * xB) * v.y;
    }
    oAB[(size_t)w * 64 + lane] = make_float2(accA * inv.x, accB * inv.y);
}

// ---------------------------------------------------------------------------
// Fused final: out = b2 + (lw0*A + lw1*B) @ W2   (interleaved input)
// ---------------------------------------------------------------------------
__global__ __launch_bounds__(256) void gemm_out_ab(const float2* __restrict__ AAB,
                                                   const float* __restrict__ W2,
                                                   const float* __restrict__ b2,
                                                   const float* __restrict__ lin_w,
                                                   float* __restrict__ out, int n) {
    __shared__ __align__(16) float sW[64 * 50];
    __shared__ __align__(16) float sA[64 * 68];
    int t = threadIdx.x;
    int row0 = blockIdx.x * 64;
    float lw0 = lin_w[0], lw1 = lin_w[1];
    for (int i = t; i < 64 * 50; i += 256) sW[i] = W2[i];
    int rows = n - row0; if (rows > 64) rows = 64;
    for (int i = t * 4; i < 8192; i += 1024) {
        int r = i >> 7, c2 = i & 127;
        float4 v = {0.f, 0.f, 0.f, 0.f};
        if (r < rows) v = *(const float4*)((const float*)&AAB[(size_t)(row0 + r) * 64] + c2);
        int dim = c2 >> 1;
        sA[r * 68 + dim] = lw0 * v.x + lw1 * v.y;
        sA[r * 68 + dim + 1] = lw0 * v.z + lw1 * v.w;
    }
    __syncthreads();
    for (int i = t; i < 64 * 50; i += 256) {
        int r = i / 50, col = i - r * 50;
        if (row0 + r >= n) continue;
        float acc = 0.f;
#pragma unroll
        for (int k = 0; k < 64; ++k) acc += sA[r * 68 + k] * sW[k * 50 + col];
        out[(size_t)(row0 + r) * 50 + col] = b2[col] + acc;
    }
}

// ---------------------------------------------------------------------------
extern "C" void kernel_launch(void* const* d_in, const int* in_sizes, int n_in,
                              void* d_out, int out_size, void* d_ws, size_t ws_size,
                              hipStream_t stream) {
    const float* h      = (const float*)d_in[0];
    const float* params = (const float*)d_in[1];
    const float* gt_w   = (const float*)d_in[2];
    const float* fc_w   = (const float*)d_in[3];
    const float* attn_l = (const float*)d_in[4];
    const float* attn_r = (const float*)d_in[5];
    const float* lin_w  = (const float*)d_in[6];
    const float* W2     = (const float*)d_in[7];
    const float* b2     = (const float*)d_in[8];
    const int*   src    = (const int*)d_in[9];
    const int*   dst    = (const int*)d_in[10];
    const int*   rel    = (const int*)d_in[11];

    const int n = in_sizes[0] / 64;      // 100000 nodes
    const int m = in_sizes[9];           // 1.8M edges
    const int C = 2, L = 2;
    float* out = (float*)d_out;

    char* base = (char*)d_ws;
    size_t off = 0;
    auto alloc = [&](size_t bytes) -> char* {
        char* p = base + off;
        off = (off + bytes + 255) & ~(size_t)255;
        return p;
    };
    const int NB = (n + NPB - 1) >> NPB_SHIFT;
    const int nchunks = (m + SC_EDGES - 1) / SC_EDGES;
    float*    filt  = (float*)alloc(L * C * 3 * sizeof(float));
    float*    Wc    = (float*)alloc((size_t)C * 64 * 64 * 4);
    int*      bcnt  = (int*)alloc((size_t)NB * 4);
    int*      bbase = (int*)alloc((size_t)(NB + 1) * 4);
    int*      bcur  = (int*)alloc((size_t)NB * 4);
    int*      rowp  = (int*)alloc((size_t)(n + 1) * 4);
    unsigned* ebuf  = (unsigned*)alloc((size_t)m * 4);
    unsigned* csr   = (unsigned*)alloc((size_t)m * 4);
    float2*   el2   = (float2*)alloc((size_t)n * 8);
    float2*   er2   = (float2*)alloc((size_t)n * 8);
    float2*   sbAB  = (float2*)alloc((size_t)n * 8);
    float2*   AAB   = (float2*)alloc((size_t)n * 64 * 8);
    float2*   BAB   = (float2*)alloc((size_t)n * 64 * 8);
    float2*   CAB   = (float2*)alloc((size_t)n * 64 * 8);

    // ---- CSR build ----
    hipMemsetAsync(bcnt, 0, (size_t)NB * 4, stream);
    mkfilt<<<1, 64, 0, stream>>>(gt_w, filt, L * C);
    combw_kernel<<<C, 256, 0, stream>>>(params, fc_w, Wc);
    bcount_kernel<<<nchunks, 256, 0, stream>>>(dst, bcnt, m, NB);
    bscan_kernel<<<1, 1024, 0, stream>>>(bcnt, bbase, bcur, NB);
    bscatter_kernel<<<nchunks, 256, 0, stream>>>(src, dst, rel, bcur, ebuf, m, NB);
    bfinal_kernel<<<NB, 256, 0, stream>>>(ebuf, bbase, rowp, csr, n, m, NB);

    const int gB = (n + 63) / 64;
    const int waveBlocks = (n + 3) / 4;

    for (int l = 0; l < L; ++l) {
        if (l == 0)
            gemm_l0<<<gB, 256, 0, stream>>>(h, Wc, BAB, n, attn_l, attn_r, el2, er2);
        else
            gemm_l1<<<gB, 256, 0, stream>>>(AAB, fc_w, BAB, n, attn_l, attn_r, el2, er2);
        int fo0 = (l * C + 0) * 3, fo1 = (l * C + 1) * 3;
        agg1_ab<<<waveBlocks, 256, 0, stream>>>(rowp, csr, filt, fo0, fo1, el2, er2,
                                                BAB, CAB, sbAB, n);
        agg2_ab<<<waveBlocks, 256, 0, stream>>>(rowp, csr, el2, er2, sbAB,
                                                CAB, AAB, n);
    }
    gemm_out_ab<<<gB, 256, 0, stream>>>(AAB, W2, b2, lin_w, out, n);
}